// Round 3
// baseline (110.953 us; speedup 1.0000x reference)
//
#include <hip/hip_runtime.h>

// ---------------------------------------------------------------------------
// metaLinear: y[t,o] = sum_j x2[t,j] * ( x1[t,:]@W[j*64+o,:] + bvec[j*64+o] )
//   T=16384, IN1=256, IN2=64 (j), OUT=64 (o).
// Round 5: barrier-free main loop at the L1-service ceiling.
//   Diagnosis: round-0 was L1-bound (4.35 MB/CU @ measured ~34 B/cyc = 53us);
//   round-4 was barrier-lockstep-bound (1 block/CU, __syncthreads per j).
//   Fix: 4 token tiles per wave (BM=128) -> each W frag global->reg load
//   feeds 4 MFMAs; waves kh(4)xjh(2) read DISJOINT frags -> per-CU global
//   demand exactly 1 MB ~= 32 B/cyc at the 13.7us MFMA floor. NO LDS ring,
//   NO barriers in the j-loop (register double-buffer only). x1 frags also
//   direct global->reg. x2 in LDS (32KB). 8-way partial reduce in 3 short
//   LDS phases at the end. 256 blocks x 512 thr, 1 block/CU, 2 waves/SIMD.
// ---------------------------------------------------------------------------

#define FRAG_SHORTS 512                  // 64 lanes * 8 bf16
#define JSTEP (2 * 16 * FRAG_SHORTS)     // shorts per j (both oh frames)
#define BIAS_OFF ((size_t)(64 * 2 * 16) * FRAG_SHORTS)   // 1048576 shorts

typedef __bf16 bf16x8 __attribute__((ext_vector_type(8)));
typedef float  f32x16 __attribute__((ext_vector_type(16)));

static __device__ __forceinline__ unsigned short f2bf(float f) {
  union { float f; unsigned u; } v; v.f = f;
  unsigned r = v.u + 0x7FFFu + ((v.u >> 16) & 1u);   // RNE
  return (unsigned short)(r >> 16);
}

static __device__ __forceinline__ bf16x8 pack8(float4 a, float4 b) {
  union { bf16x8 v; unsigned short u[8]; } r;
  r.u[0] = f2bf(a.x); r.u[1] = f2bf(a.y); r.u[2] = f2bf(a.z); r.u[3] = f2bf(a.w);
  r.u[4] = f2bf(b.x); r.u[5] = f2bf(b.y); r.u[6] = f2bf(b.z); r.u[7] = f2bf(b.w);
  return r.v;
}

// Pre-shuffle W into A-fragment order (16 frags per (j,oh)):
//   Wf[((j*2+oh)*16 + ks)*512 + lane*8 + e] =
//       bf16( W[row = 64j+32oh+(lane&31)][col = 16ks + 8*(lane>>5) + e] )
// plus 8 bias A-frames at BIAS_OFF, frame f = oh*4+jq (jq = 16-j quarter):
//   Bf[f*512 + lane*8 + e] = bf16( bvec[(jq*16 + 8*(lane>>5)+e)*64 + 32oh + (lane&31)] )
__global__ void prep_w(const float* __restrict__ W, const float* __restrict__ bv,
                       unsigned short* __restrict__ Wf) {
  int idx = blockIdx.x * 256 + threadIdx.x;   // 65536 total
  int r  = idx >> 4;                          // W row 0..4095
  int ks = idx & 15;                          // k-step 0..15
  int j   = r >> 6;
  int o   = r & 63;
  int oh  = o >> 5;
  int l31 = o & 31;
  size_t fb = ((size_t)(j * 2 + oh) * 16 + ks) * FRAG_SHORTS;

  const float4* row = (const float4*)(W + (size_t)r * 256 + ks * 16);
  float4 v0 = row[0], v1 = row[1], v2 = row[2], v3 = row[3];
  ushort4 lo0, lo1, hi0, hi1;
  lo0.x = f2bf(v0.x); lo0.y = f2bf(v0.y); lo0.z = f2bf(v0.z); lo0.w = f2bf(v0.w);
  lo1.x = f2bf(v1.x); lo1.y = f2bf(v1.y); lo1.z = f2bf(v1.z); lo1.w = f2bf(v1.w);
  hi0.x = f2bf(v2.x); hi0.y = f2bf(v2.y); hi0.z = f2bf(v2.z); hi0.w = f2bf(v2.w);
  hi1.x = f2bf(v3.x); hi1.y = f2bf(v3.y); hi1.z = f2bf(v3.z); hi1.w = f2bf(v3.w);
  *(ushort4*)&Wf[fb + l31 * 8 + 0] = lo0;            // lane l31 (lg=0)
  *(ushort4*)&Wf[fb + l31 * 8 + 4] = lo1;
  *(ushort4*)&Wf[fb + 256 + l31 * 8 + 0] = hi0;      // lane 32+l31 (lg=1)
  *(ushort4*)&Wf[fb + 256 + l31 * 8 + 4] = hi1;

  if (idx < 512) {                                   // bias A-frames
    int f   = idx >> 6;                              // 0..7 = oh*4+jq
    int ln  = idx & 63;
    int ohb = f >> 2, jq = f & 3;
    int lb  = ln & 31, lgb = ln >> 5;
    #pragma unroll
    for (int e = 0; e < 8; ++e)
      Wf[BIAS_OFF + (size_t)f * FRAG_SHORTS + ln * 8 + e] =
          f2bf(bv[(jq * 16 + 8 * lgb + e) * 64 + 32 * ohb + lb]);
  }
}

// Main fused kernel. 256 WGs x 512 threads (8 waves = kh(4) x jh(2)).
// Block = (tile-group of 128 tokens, oh). Each wave: 4 token tiles (m=0..3),
// its kh quarter of k-steps (4 frags), its jh half of j (32 j's).
__global__ __launch_bounds__(512, 2)
void meta_main(const float* __restrict__ x1, const float* __restrict__ x2,
               const unsigned short* __restrict__ Wf, float* __restrict__ out) {
  __shared__ __align__(16) unsigned char smem[102400];
  float* sX2 = (float*)smem;                    // 32 KB: x2 transposed [j][t=128]
  float* red = (float*)(smem + 32768);          // 4 slots x 4352 f32 (pad 17)

  const int tid  = threadIdx.x;
  const int lane = tid & 63;
  const int wv   = tid >> 6;
  const int kh   = wv & 3;                      // k-quarter (frags kh*4..+4)
  const int jh   = wv >> 2;                     // j half (32 j's)
  const int l31  = lane & 31;
  const int lg   = lane >> 5;

  const int bid  = blockIdx.x;
  const int oh   = bid & 1;
  const long tile0 = (long)(bid >> 1) * 128;

  // ---- stage x2 -> sX2[j][t] (only LDS staging; one barrier) ----
  {
    const float4* s2 = (const float4*)(x2 + tile0 * 64);
    #pragma unroll
    for (int it = 0; it < 4; ++it) {
      int fi4 = it * 512 + tid;
      float4 v = s2[fi4];
      int token = fi4 >> 4;                     // 0..127
      int j0    = (fi4 & 15) * 4;
      sX2[(j0 + 0) * 128 + token] = v.x;
      sX2[(j0 + 1) * 128 + token] = v.y;
      sX2[(j0 + 2) * 128 + token] = v.z;
      sX2[(j0 + 3) * 128 + token] = v.w;
    }
  }

  // ---- x1 B-frags direct global->reg: 4 tiles x 4 ks (this kh quarter) ----
  bf16x8 bf[4][4];
  #pragma unroll
  for (int m = 0; m < 4; ++m) {
    #pragma unroll
    for (int q = 0; q < 4; ++q) {
      const float* p = x1 + (size_t)(tile0 + m * 32 + l31) * 256 +
                       (kh * 4 + q) * 16 + lg * 8;
      bf[m][q] = pack8(*(const float4*)p, *(const float4*)(p + 4));
    }
  }
  __syncthreads();                              // sX2 ready

  f32x16 z;
  #pragma unroll
  for (int r = 0; r < 16; ++r) z[r] = 0.0f;

  // ---- yacc init; kh==0 waves fold the bias term (2 quarters each) ----
  f32x16 y[4];
  #pragma unroll
  for (int m = 0; m < 4; ++m) y[m] = z;
  if (kh == 0) {
    #pragma unroll
    for (int qq = 0; qq < 2; ++qq) {
      int jq = jh * 2 + qq;
      bf16x8 bias = *(const bf16x8*)(Wf + BIAS_OFF +
                                     (size_t)(oh * 4 + jq) * FRAG_SHORTS + lane * 8);
      #pragma unroll
      for (int m = 0; m < 4; ++m) {
        union { bf16x8 v; unsigned short u[8]; } xf;
        #pragma unroll
        for (int e = 0; e < 8; ++e)
          xf.u[e] = f2bf(sX2[(jq * 16 + 8 * lg + e) * 128 + m * 32 + l31]);
        y[m] = __builtin_amdgcn_mfma_f32_32x32x16_bf16(bias, xf.v, y[m], 0, 0, 0);
      }
    }
  }

  // ---- barrier-free main loop: register double-buffered W frags ----
  const unsigned short* wp =
      Wf + ((size_t)(jh * 32 * 2 + oh) * 16 + kh * 4) * FRAG_SHORTS + lane * 8;
  bf16x8 wa[4], wb[4];
  #pragma unroll
  for (int q = 0; q < 4; ++q)
    wa[q] = *(const bf16x8*)(wp + q * FRAG_SHORTS);

#define COMPUTE(WREG, J)                                                        \
  {                                                                             \
    f32x16 aA, aB;                                                              \
    aA = __builtin_amdgcn_mfma_f32_32x32x16_bf16(WREG[0], bf[0][0], z, 0, 0, 0);\
    aB = __builtin_amdgcn_mfma_f32_32x32x16_bf16(WREG[0], bf[1][0], z, 0, 0, 0);\
    aA = __builtin_amdgcn_mfma_f32_32x32x16_bf16(WREG[1], bf[0][1], aA, 0, 0, 0);\
    aB = __builtin_amdgcn_mfma_f32_32x32x16_bf16(WREG[1], bf[1][1], aB, 0, 0, 0);\
    aA = __builtin_amdgcn_mfma_f32_32x32x16_bf16(WREG[2], bf[0][2], aA, 0, 0, 0);\
    aB = __builtin_amdgcn_mfma_f32_32x32x16_bf16(WREG[2], bf[1][2], aB, 0, 0, 0);\
    aA = __builtin_amdgcn_mfma_f32_32x32x16_bf16(WREG[3], bf[0][3], aA, 0, 0, 0);\
    aB = __builtin_amdgcn_mfma_f32_32x32x16_bf16(WREG[3], bf[1][3], aB, 0, 0, 0);\
    float xs0 = sX2[(J) * 128 + l31];                                           \
    float xs1 = sX2[(J) * 128 + 32 + l31];                                      \
    _Pragma("unroll")                                                           \
    for (int r = 0; r < 16; ++r) {                                              \
      y[0][r] += xs0 * aA[r];                                                   \
      y[1][r] += xs1 * aB[r];                                                   \
    }                                                                           \
    aA = __builtin_amdgcn_mfma_f32_32x32x16_bf16(WREG[0], bf[2][0], z, 0, 0, 0);\
    aB = __builtin_amdgcn_mfma_f32_32x32x16_bf16(WREG[0], bf[3][0], z, 0, 0, 0);\
    aA = __builtin_amdgcn_mfma_f32_32x32x16_bf16(WREG[1], bf[2][1], aA, 0, 0, 0);\
    aB = __builtin_amdgcn_mfma_f32_32x32x16_bf16(WREG[1], bf[3][1], aB, 0, 0, 0);\
    aA = __builtin_amdgcn_mfma_f32_32x32x16_bf16(WREG[2], bf[2][2], aA, 0, 0, 0);\
    aB = __builtin_amdgcn_mfma_f32_32x32x16_bf16(WREG[2], bf[3][2], aB, 0, 0, 0);\
    aA = __builtin_amdgcn_mfma_f32_32x32x16_bf16(WREG[3], bf[2][3], aA, 0, 0, 0);\
    aB = __builtin_amdgcn_mfma_f32_32x32x16_bf16(WREG[3], bf[3][3], aB, 0, 0, 0);\
    float xs2 = sX2[(J) * 128 + 64 + l31];                                      \
    float xs3 = sX2[(J) * 128 + 96 + l31];                                      \
    _Pragma("unroll")                                                           \
    for (int r = 0; r < 16; ++r) {                                              \
      y[2][r] += xs2 * aA[r];                                                   \
      y[3][r] += xs3 * aB[r];                                                   \
    }                                                                           \
  }

  for (int i = 0; i < 32; i += 2) {
    const int jg = jh * 32 + i;
    #pragma unroll
    for (int q = 0; q < 4; ++q)
      wb[q] = *(const bf16x8*)(wp + JSTEP + q * FRAG_SHORTS);
    COMPUTE(wa, jg);
    if (i + 2 < 32) {
      #pragma unroll
      for (int q = 0; q < 4; ++q)
        wa[q] = *(const bf16x8*)(wp + 2 * JSTEP + q * FRAG_SHORTS);
    }
    COMPUTE(wb, jg + 1);
    wp += 2 * JSTEP;
  }
#undef COMPUTE

  // ---- 8-way partial reduction in 3 LDS phases (pad-17, conflict-free) ----
#define RED_W(S)                                                   \
  { float* b = red + (S) * 4352;                                   \
    _Pragma("unroll") for (int m = 0; m < 4; ++m)                  \
      _Pragma("unroll") for (int r = 0; r < 16; ++r)               \
        b[(m * 64 + lane) * 17 + r] = y[m][r]; }
#define RED_A(S)                                                   \
  { const float* b = red + (S) * 4352;                             \
    _Pragma("unroll") for (int m = 0; m < 4; ++m)                  \
      _Pragma("unroll") for (int r = 0; r < 16; ++r)               \
        y[m][r] += b[(m * 64 + lane) * 17 + r]; }

  if (kh >= 2) RED_W((kh - 2) * 2 + jh);
  __syncthreads();
  if (kh < 2)  RED_A(kh * 2 + jh);
  __syncthreads();
  if (kh == 1) RED_W(jh);
  __syncthreads();
  if (kh == 0) RED_A(jh);
  __syncthreads();
  if (kh == 0 && jh == 1) RED_W(0);
  __syncthreads();
  if (wv == 0) {
    RED_A(0);
    // D layout: col = t = l31, row(o_local) = (r&3) + 8*(r>>2) + 4*lg
    #pragma unroll
    for (int m = 0; m < 4; ++m) {
      float* yo = out + (tile0 + m * 32 + l31) * 64 + oh * 32;
      #pragma unroll
      for (int rq = 0; rq < 4; ++rq) {
        float4 v = make_float4(y[m][4 * rq + 0], y[m][4 * rq + 1],
                               y[m][4 * rq + 2], y[m][4 * rq + 3]);
        *(float4*)(yo + 8 * rq + 4 * lg) = v;
      }
    }
  }
#undef RED_W
#undef RED_A
}

extern "C" void kernel_launch(void* const* d_in, const int* in_sizes, int n_in,
                              void* d_out, int out_size, void* d_ws, size_t ws_size,
                              hipStream_t stream) {
  const float* x1 = (const float*)d_in[0];   // (4,4096,256) f32
  const float* x2 = (const float*)d_in[1];   // (4,4096,64)  f32
  const float* W  = (const float*)d_in[2];   // (4096,256)   f32
  const float* bv = (const float*)d_in[3];   // (4096,)      f32
  float* y = (float*)d_out;                  // (4,4096,64)  f32
  unsigned short* Wf = (unsigned short*)d_ws;  // 2 MB frags + 8 KB bias frames

  prep_w<<<256, 256, 0, stream>>>(W, bv, Wf);
  meta_main<<<256, 512, 0, stream>>>(x1, x2, Wf, y);
}

// Round 4
// 110.868 us; speedup vs baseline: 1.0008x; 1.0008x over previous
//
#include <hip/hip_runtime.h>

// ---------------------------------------------------------------------------
// metaLinear: y[t,o] = sum_j x2[t,j] * ( x1[t,:]@W[j*64+o,:] + bvec[j*64+o] )
//   T=16384, IN1=256, IN2=64 (j), OUT=64 (o).
// Round 6: SAME structure as round 5 (barrier-free j-loop, 4 token tiles per
// wave, register double-buffered W frags) with ONE change: pin the register
// budget via amdgpu_waves_per_eu(2,2).
//   Diagnosis: rounds 0/4/5 all register-starved. __launch_bounds__(512,2)
//   sets only a MIN waves/EU; the backend's occupancy heuristic targeted 4
//   waves/EU (128-VGPR cap) and rematerialized the "register-resident"
//   x1/W fragments from global inside the j-loop (no scratch stores -> WRITE
//   clean; L2 reloads invisible in FETCH), putting L2 latency in front of
//   every MFMA: ~3000 cyc/j vs ~400 of pipe work. LDS=100KB caps us at
//   1 block/CU = 2 waves/EU anyway, so the squeezed occupancy bought nothing.
//   Fix: min=max=2 waves/EU -> 256-VGPR budget, loop truly register-resident.
// ---------------------------------------------------------------------------

#define FRAG_SHORTS 512                  // 64 lanes * 8 bf16
#define JSTEP (2 * 16 * FRAG_SHORTS)     // shorts per j (both oh frames)
#define BIAS_OFF ((size_t)(64 * 2 * 16) * FRAG_SHORTS)   // 1048576 shorts

typedef __bf16 bf16x8 __attribute__((ext_vector_type(8)));
typedef float  f32x16 __attribute__((ext_vector_type(16)));

static __device__ __forceinline__ unsigned short f2bf(float f) {
  union { float f; unsigned u; } v; v.f = f;
  unsigned r = v.u + 0x7FFFu + ((v.u >> 16) & 1u);   // RNE
  return (unsigned short)(r >> 16);
}

static __device__ __forceinline__ bf16x8 pack8(float4 a, float4 b) {
  union { bf16x8 v; unsigned short u[8]; } r;
  r.u[0] = f2bf(a.x); r.u[1] = f2bf(a.y); r.u[2] = f2bf(a.z); r.u[3] = f2bf(a.w);
  r.u[4] = f2bf(b.x); r.u[5] = f2bf(b.y); r.u[6] = f2bf(b.z); r.u[7] = f2bf(b.w);
  return r.v;
}

// Pre-shuffle W into A-fragment order (16 frags per (j,oh)):
//   Wf[((j*2+oh)*16 + ks)*512 + lane*8 + e] =
//       bf16( W[row = 64j+32oh+(lane&31)][col = 16ks + 8*(lane>>5) + e] )
// plus 8 bias A-frames at BIAS_OFF, frame f = oh*4+jq (jq = 16-j quarter):
//   Bf[f*512 + lane*8 + e] = bf16( bvec[(jq*16 + 8*(lane>>5)+e)*64 + 32oh + (lane&31)] )
__global__ void prep_w(const float* __restrict__ W, const float* __restrict__ bv,
                       unsigned short* __restrict__ Wf) {
  int idx = blockIdx.x * 256 + threadIdx.x;   // 65536 total
  int r  = idx >> 4;                          // W row 0..4095
  int ks = idx & 15;                          // k-step 0..15
  int j   = r >> 6;
  int o   = r & 63;
  int oh  = o >> 5;
  int l31 = o & 31;
  size_t fb = ((size_t)(j * 2 + oh) * 16 + ks) * FRAG_SHORTS;

  const float4* row = (const float4*)(W + (size_t)r * 256 + ks * 16);
  float4 v0 = row[0], v1 = row[1], v2 = row[2], v3 = row[3];
  ushort4 lo0, lo1, hi0, hi1;
  lo0.x = f2bf(v0.x); lo0.y = f2bf(v0.y); lo0.z = f2bf(v0.z); lo0.w = f2bf(v0.w);
  lo1.x = f2bf(v1.x); lo1.y = f2bf(v1.y); lo1.z = f2bf(v1.z); lo1.w = f2bf(v1.w);
  hi0.x = f2bf(v2.x); hi0.y = f2bf(v2.y); hi0.z = f2bf(v2.z); hi0.w = f2bf(v2.w);
  hi1.x = f2bf(v3.x); hi1.y = f2bf(v3.y); hi1.z = f2bf(v3.z); hi1.w = f2bf(v3.w);
  *(ushort4*)&Wf[fb + l31 * 8 + 0] = lo0;            // lane l31 (lg=0)
  *(ushort4*)&Wf[fb + l31 * 8 + 4] = lo1;
  *(ushort4*)&Wf[fb + 256 + l31 * 8 + 0] = hi0;      // lane 32+l31 (lg=1)
  *(ushort4*)&Wf[fb + 256 + l31 * 8 + 4] = hi1;

  if (idx < 512) {                                   // bias A-frames
    int f   = idx >> 6;                              // 0..7 = oh*4+jq
    int ln  = idx & 63;
    int ohb = f >> 2, jq = f & 3;
    int lb  = ln & 31, lgb = ln >> 5;
    #pragma unroll
    for (int e = 0; e < 8; ++e)
      Wf[BIAS_OFF + (size_t)f * FRAG_SHORTS + ln * 8 + e] =
          f2bf(bv[(jq * 16 + 8 * lgb + e) * 64 + 32 * ohb + lb]);
  }
}

// Main fused kernel. 256 WGs x 512 threads (8 waves = kh(4) x jh(2)).
// Block = (tile-group of 128 tokens, oh). Each wave: 4 token tiles (m=0..3),
// its kh quarter of k-steps (4 frags), its jh half of j (32 j's).
__global__
__attribute__((amdgpu_flat_work_group_size(512, 512), amdgpu_waves_per_eu(2, 2)))
void meta_main(const float* __restrict__ x1, const float* __restrict__ x2,
               const unsigned short* __restrict__ Wf, float* __restrict__ out) {
  __shared__ __align__(16) unsigned char smem[102400];
  float* sX2 = (float*)smem;                    // 32 KB: x2 transposed [j][t=128]
  float* red = (float*)(smem + 32768);          // 4 slots x 4352 f32 (pad 17)

  const int tid  = threadIdx.x;
  const int lane = tid & 63;
  const int wv   = tid >> 6;
  const int kh   = wv & 3;                      // k-quarter (frags kh*4..+4)
  const int jh   = wv >> 2;                     // j half (32 j's)
  const int l31  = lane & 31;
  const int lg   = lane >> 5;

  const int bid  = blockIdx.x;
  const int oh   = bid & 1;
  const long tile0 = (long)(bid >> 1) * 128;

  // ---- stage x2 -> sX2[j][t] (only LDS staging; one barrier) ----
  {
    const float4* s2 = (const float4*)(x2 + tile0 * 64);
    #pragma unroll
    for (int it = 0; it < 4; ++it) {
      int fi4 = it * 512 + tid;
      float4 v = s2[fi4];
      int token = fi4 >> 4;                     // 0..127
      int j0    = (fi4 & 15) * 4;
      sX2[(j0 + 0) * 128 + token] = v.x;
      sX2[(j0 + 1) * 128 + token] = v.y;
      sX2[(j0 + 2) * 128 + token] = v.z;
      sX2[(j0 + 3) * 128 + token] = v.w;
    }
  }

  // ---- x1 B-frags direct global->reg: 4 tiles x 4 ks (this kh quarter) ----
  bf16x8 bf[4][4];
  #pragma unroll
  for (int m = 0; m < 4; ++m) {
    #pragma unroll
    for (int q = 0; q < 4; ++q) {
      const float* p = x1 + (size_t)(tile0 + m * 32 + l31) * 256 +
                       (kh * 4 + q) * 16 + lg * 8;
      bf[m][q] = pack8(*(const float4*)p, *(const float4*)(p + 4));
    }
  }
  __syncthreads();                              // sX2 ready

  f32x16 z;
  #pragma unroll
  for (int r = 0; r < 16; ++r) z[r] = 0.0f;

  // ---- yacc init; kh==0 waves fold the bias term (2 quarters each) ----
  f32x16 y[4];
  #pragma unroll
  for (int m = 0; m < 4; ++m) y[m] = z;
  if (kh == 0) {
    #pragma unroll
    for (int qq = 0; qq < 2; ++qq) {
      int jq = jh * 2 + qq;
      bf16x8 bias = *(const bf16x8*)(Wf + BIAS_OFF +
                                     (size_t)(oh * 4 + jq) * FRAG_SHORTS + lane * 8);
      #pragma unroll
      for (int m = 0; m < 4; ++m) {
        union { bf16x8 v; unsigned short u[8]; } xf;
        #pragma unroll
        for (int e = 0; e < 8; ++e)
          xf.u[e] = f2bf(sX2[(jq * 16 + 8 * lg + e) * 128 + m * 32 + l31]);
        y[m] = __builtin_amdgcn_mfma_f32_32x32x16_bf16(bias, xf.v, y[m], 0, 0, 0);
      }
    }
  }

  // ---- barrier-free main loop: register double-buffered W frags ----
  const unsigned short* wp =
      Wf + ((size_t)(jh * 32 * 2 + oh) * 16 + kh * 4) * FRAG_SHORTS + lane * 8;
  bf16x8 wa[4], wb[4];
  #pragma unroll
  for (int q = 0; q < 4; ++q)
    wa[q] = *(const bf16x8*)(wp + q * FRAG_SHORTS);

#define COMPUTE(WREG, J)                                                        \
  {                                                                             \
    f32x16 aA, aB;                                                              \
    aA = __builtin_amdgcn_mfma_f32_32x32x16_bf16(WREG[0], bf[0][0], z, 0, 0, 0);\
    aB = __builtin_amdgcn_mfma_f32_32x32x16_bf16(WREG[0], bf[1][0], z, 0, 0, 0);\
    aA = __builtin_amdgcn_mfma_f32_32x32x16_bf16(WREG[1], bf[0][1], aA, 0, 0, 0);\
    aB = __builtin_amdgcn_mfma_f32_32x32x16_bf16(WREG[1], bf[1][1], aB, 0, 0, 0);\
    aA = __builtin_amdgcn_mfma_f32_32x32x16_bf16(WREG[2], bf[0][2], aA, 0, 0, 0);\
    aB = __builtin_amdgcn_mfma_f32_32x32x16_bf16(WREG[2], bf[1][2], aB, 0, 0, 0);\
    aA = __builtin_amdgcn_mfma_f32_32x32x16_bf16(WREG[3], bf[0][3], aA, 0, 0, 0);\
    aB = __builtin_amdgcn_mfma_f32_32x32x16_bf16(WREG[3], bf[1][3], aB, 0, 0, 0);\
    float xs0 = sX2[(J) * 128 + l31];                                           \
    float xs1 = sX2[(J) * 128 + 32 + l31];                                      \
    _Pragma("unroll")                                                           \
    for (int r = 0; r < 16; ++r) {                                              \
      y[0][r] += xs0 * aA[r];                                                   \
      y[1][r] += xs1 * aB[r];                                                   \
    }                                                                           \
    aA = __builtin_amdgcn_mfma_f32_32x32x16_bf16(WREG[0], bf[2][0], z, 0, 0, 0);\
    aB = __builtin_amdgcn_mfma_f32_32x32x16_bf16(WREG[0], bf[3][0], z, 0, 0, 0);\
    aA = __builtin_amdgcn_mfma_f32_32x32x16_bf16(WREG[1], bf[2][1], aA, 0, 0, 0);\
    aB = __builtin_amdgcn_mfma_f32_32x32x16_bf16(WREG[1], bf[3][1], aB, 0, 0, 0);\
    aA = __builtin_amdgcn_mfma_f32_32x32x16_bf16(WREG[2], bf[2][2], aA, 0, 0, 0);\
    aB = __builtin_amdgcn_mfma_f32_32x32x16_bf16(WREG[2], bf[3][2], aB, 0, 0, 0);\
    aA = __builtin_amdgcn_mfma_f32_32x32x16_bf16(WREG[3], bf[2][3], aA, 0, 0, 0);\
    aB = __builtin_amdgcn_mfma_f32_32x32x16_bf16(WREG[3], bf[3][3], aB, 0, 0, 0);\
    float xs2 = sX2[(J) * 128 + 64 + l31];                                      \
    float xs3 = sX2[(J) * 128 + 96 + l31];                                      \
    _Pragma("unroll")                                                           \
    for (int r = 0; r < 16; ++r) {                                              \
      y[2][r] += xs2 * aA[r];                                                   \
      y[3][r] += xs3 * aB[r];                                                   \
    }                                                                           \
  }

  for (int i = 0; i < 32; i += 2) {
    const int jg = jh * 32 + i;
    #pragma unroll
    for (int q = 0; q < 4; ++q)
      wb[q] = *(const bf16x8*)(wp + JSTEP + q * FRAG_SHORTS);
    COMPUTE(wa, jg);
    if (i + 2 < 32) {
      #pragma unroll
      for (int q = 0; q < 4; ++q)
        wa[q] = *(const bf16x8*)(wp + 2 * JSTEP + q * FRAG_SHORTS);
    }
    COMPUTE(wb, jg + 1);
    wp += 2 * JSTEP;
  }
#undef COMPUTE

  // ---- 8-way partial reduction in 3 LDS phases (pad-17, conflict-free) ----
#define RED_W(S)                                                   \
  { float* b = red + (S) * 4352;                                   \
    _Pragma("unroll") for (int m = 0; m < 4; ++m)                  \
      _Pragma("unroll") for (int r = 0; r < 16; ++r)               \
        b[(m * 64 + lane) * 17 + r] = y[m][r]; }
#define RED_A(S)                                                   \
  { const float* b = red + (S) * 4352;                             \
    _Pragma("unroll") for (int m = 0; m < 4; ++m)                  \
      _Pragma("unroll") for (int r = 0; r < 16; ++r)               \
        y[m][r] += b[(m * 64 + lane) * 17 + r]; }

  if (kh >= 2) RED_W((kh - 2) * 2 + jh);
  __syncthreads();
  if (kh < 2)  RED_A(kh * 2 + jh);
  __syncthreads();
  if (kh == 1) RED_W(jh);
  __syncthreads();
  if (kh == 0) RED_A(jh);
  __syncthreads();
  if (kh == 0 && jh == 1) RED_W(0);
  __syncthreads();
  if (wv == 0) {
    RED_A(0);
    // D layout: col = t = l31, row(o_local) = (r&3) + 8*(r>>2) + 4*lg
    #pragma unroll
    for (int m = 0; m < 4; ++m) {
      float* yo = out + (tile0 + m * 32 + l31) * 64 + oh * 32;
      #pragma unroll
      for (int rq = 0; rq < 4; ++rq) {
        float4 v = make_float4(y[m][4 * rq + 0], y[m][4 * rq + 1],
                               y[m][4 * rq + 2], y[m][4 * rq + 3]);
        *(float4*)(yo + 8 * rq + 4 * lg) = v;
      }
    }
  }
#undef RED_W
#undef RED_A
}

extern "C" void kernel_launch(void* const* d_in, const int* in_sizes, int n_in,
                              void* d_out, int out_size, void* d_ws, size_t ws_size,
                              hipStream_t stream) {
  const float* x1 = (const float*)d_in[0];   // (4,4096,256) f32
  const float* x2 = (const float*)d_in[1];   // (4,4096,64)  f32
  const float* W  = (const float*)d_in[2];   // (4096,256)   f32
  const float* bv = (const float*)d_in[3];   // (4096,)      f32
  float* y = (float*)d_out;                  // (4,4096,64)  f32
  unsigned short* Wf = (unsigned short*)d_ws;  // 2 MB frags + 8 KB bias frames

  prep_w<<<256, 256, 0, stream>>>(W, bv, Wf);
  meta_main<<<256, 512, 0, stream>>>(x1, x2, Wf, y);
}